// Round 6
// baseline (189.591 us; speedup 1.0000x reference)
//
#include <hip/hip_runtime.h>

#define SEQ      512
#define BATCH    64
#define NTAG     64
#define STARTTAG 62
#define ENDTAG   63
#define TILE     4096      // dwords per (t,b) tile
#define NBUF     8
#define HALF     256
#define L2E      1.44269504088896340736f
#define LN2      0.69314718055994530942f

typedef float f32x4 __attribute__((ext_vector_type(4)));
typedef const __attribute__((address_space(1))) unsigned int* gp_t;
typedef __attribute__((address_space(3))) unsigned int* lp_t;

__device__ __forceinline__ void dma16(const float* g, float* l) {
    __builtin_amdgcn_global_load_lds((gp_t)g, (lp_t)l, 16, 0, 0);
}
__device__ __forceinline__ void dma4(const float* g, float* l) {
    __builtin_amdgcn_global_load_lds((gp_t)g, (lp_t)l, 4, 0, 0);
}
__device__ __forceinline__ unsigned lofs(const void* p) {
    return (unsigned)(size_t)(const __attribute__((address_space(3))) char*)p;
}
__device__ __forceinline__ float rfl(float v) {
    return __int_as_float(__builtin_amdgcn_readfirstlane(__float_as_int(v)));
}

// All hot-loop LDS ops are inline asm so the compiler's waitcnt-insertion pass
// has NO tracked consumer of the global_load_lds DMAs -> no forced vmcnt(0).
#define LDSR4(r, a, O) asm volatile("ds_read_b128 %0, %1 offset:" O : "=v"(r) : "v"(a))
#define LDSR1(r, a)    asm volatile("ds_read_b32 %0, %1"  : "=v"(r) : "v"(a))
#define LDSW4(a, v)    asm volatile("ds_write_b128 %0, %1" :: "v"(a), "v"(v))
#define LDSW1(a, v)    asm volatile("ds_write_b32 %0, %1"  :: "v"(a), "v"(v))
#define WAITV(N)  asm volatile("s_waitcnt vmcnt(" #N ")" ::: "memory")
#define WAITL0()  do { asm volatile("s_waitcnt lgkmcnt(0)" ::: "memory"); \
                       __builtin_amdgcn_sched_barrier(0); } while (0)

#define EPART(S, A) do { \
    p0 += __builtin_amdgcn_exp2f(fmaf((S).x, L2E, (A))); \
    p1 += __builtin_amdgcn_exp2f(fmaf((S).y, L2E, (A))); \
    p2 += __builtin_amdgcn_exp2f(fmaf((S).z, L2E, (A))); \
    p3 += __builtin_amdgcn_exp2f(fmaf((S).w, L2E, (A))); } while (0)

// ---- consumer: identical to the round-3 kernel that passed (absmax 0.0) ----
template<int DIR>
__device__ void run_half(const float* __restrict__ scores, float* __restrict__ ws,
                         float* tiles, float* curls, float* initrow,
                         int b, int l, int w)
{
    const unsigned tbase = lofs(tiles);
    const unsigned cbase = lofs(curls);

    int goff[8];
    #pragma unroll
    for (int q = 0; q < 8; ++q) {
        if (DIR == 0) {
            goff[q] = 512 * q + 64 * (l >> 3) + 32 * w + 4 * (l & 7);
        } else {
            const int iloc = 4 * q + (l >> 4);
            const int col  = (4 * (l & 15)) ^ (4 * (iloc & 7));
            goff[q] = (32 * w + iloc) * 64 + col;
        }
    }
    const int ldst0 = w * 2048;

    {
        const float* t0 = scores + ((size_t)(DIR ? (SEQ - 1) : 0) * BATCH + b) * TILE;
        const float* isrc = DIR ? (t0 + l * 64 + ENDTAG) : (t0 + STARTTAG * 64 + l);
        dma4(isrc, initrow + w * 64);
        #pragma unroll
        for (int k = 1; k <= 7; ++k) {
            const int t = DIR ? (SEQ - 1 - k) : k;
            const float* gb = scores + ((size_t)t * BATCH + b) * TILE;
            float* db = tiles + (size_t)(k & 7) * TILE + ldst0;
            #pragma unroll
            for (int q = 0; q < 8; ++q) dma16(gb + goff[q], db + 256 * q);
        }
    }
    WAITV(56);
    float iv; LDSR1(iv, lofs(initrow) + (unsigned)(w * 256 + l * 4));
    WAITL0();
    LDSW1(cbase + (unsigned)(l * 4), iv);
    float M = rfl(iv);

    unsigned laneT, curR, curW;
    if (DIR == 0) {
        laneT = tbase + (unsigned)(w * 8192 + (l >> 3) * 1024 + (l & 7) * 16);
        curR  = cbase + (unsigned)((l >> 3) * 32);
        curW  = cbase + (unsigned)(128 * w + 16 * (l & 7));
    } else {
        laneT = tbase + (unsigned)(w * 8192 + (l & 31) * 256 + (l >> 5) * 128 + (l & 7) * 16);
        curR  = cbase + (unsigned)((l >> 5) * 128);
        curW  = cbase + (unsigned)(128 * w + (l & 31) * 4);
    }

    f32x4 v4; float v1 = 0.f;

    for (int k = 1; k < HALF; ++k) {
        const float am = -M * L2E;
        WAITV(48);
        const unsigned ta = laneT + (unsigned)((k & 7) * 16384);
        const unsigned ca = curR + (unsigned)(((k + 1) & 1) * 256);

        if (DIR == 0) {
            f32x4 s0, s1, s2, s3, s4, s5, s6, s7, c0, c1;
            LDSR4(s0, ta, "0");   LDSR4(s1, ta, "128");
            LDSR4(s2, ta, "256"); LDSR4(s3, ta, "384");
            LDSR4(s4, ta, "512"); LDSR4(s5, ta, "640");
            LDSR4(s6, ta, "768"); LDSR4(s7, ta, "896");
            LDSR4(c0, ca, "0");   LDSR4(c1, ca, "16");

            {
                int kk = k + 7; if (kk > HALF - 1) kk = HALF - 1;
                const int t = DIR ? (SEQ - 1 - kk) : kk;
                const float* gb = scores + ((size_t)t * BATCH + b) * TILE;
                float* db = tiles + (size_t)((k + 7) & 7) * TILE + ldst0;
                #pragma unroll
                for (int q = 0; q < 8; ++q) dma16(gb + goff[q], db + 256 * q);
            }
            WAITL0();

            float p0 = 0.f, p1 = 0.f, p2 = 0.f, p3 = 0.f;
            EPART(s0, fmaf(c0.x, L2E, am));
            EPART(s1, fmaf(c0.y, L2E, am));
            EPART(s2, fmaf(c0.z, L2E, am));
            EPART(s3, fmaf(c0.w, L2E, am));
            EPART(s4, fmaf(c1.x, L2E, am));
            EPART(s5, fmaf(c1.y, L2E, am));
            EPART(s6, fmaf(c1.z, L2E, am));
            EPART(s7, fmaf(c1.w, L2E, am));

            p0 += __shfl_xor(p0, 8);  p1 += __shfl_xor(p1, 8);
            p2 += __shfl_xor(p2, 8);  p3 += __shfl_xor(p3, 8);
            p0 += __shfl_xor(p0, 16); p1 += __shfl_xor(p1, 16);
            p2 += __shfl_xor(p2, 16); p3 += __shfl_xor(p3, 16);
            p0 += __shfl_xor(p0, 32); p1 += __shfl_xor(p1, 32);
            p2 += __shfl_xor(p2, 32); p3 += __shfl_xor(p3, 32);

            v4.x = fmaf(__builtin_amdgcn_logf(p0), LN2, M);
            v4.y = fmaf(__builtin_amdgcn_logf(p1), LN2, M);
            v4.z = fmaf(__builtin_amdgcn_logf(p2), LN2, M);
            v4.w = fmaf(__builtin_amdgcn_logf(p3), LN2, M);
            M = rfl(v4.x);
            if (l < 8) LDSW4(curW + (unsigned)((k & 1) * 256), v4);
        } else {
            f32x4 s0, s1, s2, s3, s4, s5, s6, s7, c0, c1, c2, c3, c4, c5, c6, c7;
            LDSR4(s0, ta ^ 0u,   "0"); LDSR4(s1, ta ^ 16u,  "0");
            LDSR4(s2, ta ^ 32u,  "0"); LDSR4(s3, ta ^ 48u,  "0");
            LDSR4(s4, ta ^ 64u,  "0"); LDSR4(s5, ta ^ 80u,  "0");
            LDSR4(s6, ta ^ 96u,  "0"); LDSR4(s7, ta ^ 112u, "0");
            LDSR4(c0, ca, "0");  LDSR4(c1, ca, "16");
            LDSR4(c2, ca, "32"); LDSR4(c3, ca, "48");
            LDSR4(c4, ca, "64"); LDSR4(c5, ca, "80");
            LDSR4(c6, ca, "96"); LDSR4(c7, ca, "112");

            {
                int kk = k + 7; if (kk > HALF - 1) kk = HALF - 1;
                const int t = DIR ? (SEQ - 1 - kk) : kk;
                const float* gb = scores + ((size_t)t * BATCH + b) * TILE;
                float* db = tiles + (size_t)((k + 7) & 7) * TILE + ldst0;
                #pragma unroll
                for (int q = 0; q < 8; ++q) dma16(gb + goff[q], db + 256 * q);
            }
            WAITL0();

            float p0 = 0.f, p1 = 0.f, p2 = 0.f, p3 = 0.f;
            p0 += __builtin_amdgcn_exp2f(fmaf(s0.x, L2E, fmaf(c0.x, L2E, am)));
            p1 += __builtin_amdgcn_exp2f(fmaf(s0.y, L2E, fmaf(c0.y, L2E, am)));
            p2 += __builtin_amdgcn_exp2f(fmaf(s0.z, L2E, fmaf(c0.z, L2E, am)));
            p3 += __builtin_amdgcn_exp2f(fmaf(s0.w, L2E, fmaf(c0.w, L2E, am)));
            p0 += __builtin_amdgcn_exp2f(fmaf(s1.x, L2E, fmaf(c1.x, L2E, am)));
            p1 += __builtin_amdgcn_exp2f(fmaf(s1.y, L2E, fmaf(c1.y, L2E, am)));
            p2 += __builtin_amdgcn_exp2f(fmaf(s1.z, L2E, fmaf(c1.z, L2E, am)));
            p3 += __builtin_amdgcn_exp2f(fmaf(s1.w, L2E, fmaf(c1.w, L2E, am)));
            p0 += __builtin_amdgcn_exp2f(fmaf(s2.x, L2E, fmaf(c2.x, L2E, am)));
            p1 += __builtin_amdgcn_exp2f(fmaf(s2.y, L2E, fmaf(c2.y, L2E, am)));
            p2 += __builtin_amdgcn_exp2f(fmaf(s2.z, L2E, fmaf(c2.z, L2E, am)));
            p3 += __builtin_amdgcn_exp2f(fmaf(s2.w, L2E, fmaf(c2.w, L2E, am)));
            p0 += __builtin_amdgcn_exp2f(fmaf(s3.x, L2E, fmaf(c3.x, L2E, am)));
            p1 += __builtin_amdgcn_exp2f(fmaf(s3.y, L2E, fmaf(c3.y, L2E, am)));
            p2 += __builtin_amdgcn_exp2f(fmaf(s3.z, L2E, fmaf(c3.z, L2E, am)));
            p3 += __builtin_amdgcn_exp2f(fmaf(s3.w, L2E, fmaf(c3.w, L2E, am)));
            p0 += __builtin_amdgcn_exp2f(fmaf(s4.x, L2E, fmaf(c4.x, L2E, am)));
            p1 += __builtin_amdgcn_exp2f(fmaf(s4.y, L2E, fmaf(c4.y, L2E, am)));
            p2 += __builtin_amdgcn_exp2f(fmaf(s4.z, L2E, fmaf(c4.z, L2E, am)));
            p3 += __builtin_amdgcn_exp2f(fmaf(s4.w, L2E, fmaf(c4.w, L2E, am)));
            p0 += __builtin_amdgcn_exp2f(fmaf(s5.x, L2E, fmaf(c5.x, L2E, am)));
            p1 += __builtin_amdgcn_exp2f(fmaf(s5.y, L2E, fmaf(c5.y, L2E, am)));
            p2 += __builtin_amdgcn_exp2f(fmaf(s5.z, L2E, fmaf(c5.z, L2E, am)));
            p3 += __builtin_amdgcn_exp2f(fmaf(s5.w, L2E, fmaf(c5.w, L2E, am)));
            p0 += __builtin_amdgcn_exp2f(fmaf(s6.x, L2E, fmaf(c6.x, L2E, am)));
            p1 += __builtin_amdgcn_exp2f(fmaf(s6.y, L2E, fmaf(c6.y, L2E, am)));
            p2 += __builtin_amdgcn_exp2f(fmaf(s6.z, L2E, fmaf(c6.z, L2E, am)));
            p3 += __builtin_amdgcn_exp2f(fmaf(s6.w, L2E, fmaf(c6.w, L2E, am)));
            p0 += __builtin_amdgcn_exp2f(fmaf(s7.x, L2E, fmaf(c7.x, L2E, am)));
            p1 += __builtin_amdgcn_exp2f(fmaf(s7.y, L2E, fmaf(c7.y, L2E, am)));
            p2 += __builtin_amdgcn_exp2f(fmaf(s7.z, L2E, fmaf(c7.z, L2E, am)));
            p3 += __builtin_amdgcn_exp2f(fmaf(s7.w, L2E, fmaf(c7.w, L2E, am)));

            float p = (p0 + p1) + (p2 + p3);
            p += __shfl_xor(p, 32);
            v1 = fmaf(__builtin_amdgcn_logf(p), LN2, M);
            M = rfl(v1);
            if (l < 32) LDSW1(curW + (unsigned)((k & 1) * 256), v1);
        }

        WAITL0();
        __builtin_amdgcn_s_barrier();
    }

    WAITV(0);
    if (DIR == 0) {
        if (l < 8)
            *(f32x4*)(ws + (size_t)b * 64 + 32 * w + 4 * (l & 7)) = v4;
    } else {
        if (l < 32)
            ws[(size_t)BATCH * NTAG + (size_t)b * 64 + 32 * w + l] = v1;
    }
}

// ---- L2-warmer: streams chain (b,dir) tiles 8..255 into a throwaway LDS
// scratch via global_load_lds. Never reads LDS, no barriers, no flags.
// Self-balancing: its rate is capped by its own HBM fabric share, the paired
// consumer's rate is >= its own share, so the lead never exceeds ~7 tiles
// (112 KB < the chain's ~256 KB L2 share). When the consumer catches up, the
// warmer's reads become L2-hits (free) until it is ahead again.
__device__ void run_warm(const float* __restrict__ scores, float* tiles,
                         int b, int dir, int l, int w)
{
    const int g0 = 2048 * w;               // this wave's half-tile (dwords)
    float* db = tiles + g0;                // throwaway scratch (wave-uniform)
    for (int k = 8; k < HALF; ++k) {
        const int t = dir ? (SEQ - 1 - k) : k;
        const float* gb = scores + ((size_t)t * BATCH + b) * TILE + g0 + 4 * l;
        #pragma unroll
        for (int q = 0; q < 8; ++q) dma16(gb + 256 * q, db + 256 * q);
        WAITV(47);                         // pace: ~6 tiles in flight per wave
    }
    WAITV(0);
}

__global__ __launch_bounds__(128, 1)
void crf_half_kernel(const float* __restrict__ scores, float* __restrict__ ws)
{
    __shared__ __align__(128) float tiles[NBUF * TILE];   // 128 KiB ring
    __shared__ __align__(128) float curls[2 * NTAG];
    __shared__ __align__(16)  float initrow[2 * NTAG];
    const int tid = (int)threadIdx.x;
    const int l = tid & 63, w = tid >> 6;
    const int bid = (int)blockIdx.x;
    if (bid < 2 * BATCH) {
        const int b = bid >> 1, dir = bid & 1;
        if (dir == 0) run_half<0>(scores, ws, tiles, curls, initrow, b, l, w);
        else          run_half<1>(scores, ws, tiles, curls, initrow, b, l, w);
    } else {
        const int cid = bid - 2 * BATCH;       // paired chain; bid%8 == cid%8 -> same XCD
        run_warm(scores, tiles, cid >> 1, cid & 1, l, w);
    }
}

__global__ __launch_bounds__(64, 1)
void crf_combine_kernel(const float* __restrict__ scores,
                        const int* __restrict__ target,
                        const int* __restrict__ mask,
                        const float* __restrict__ ws,
                        float* __restrict__ out)
{
    const int b = (int)blockIdx.x, l = (int)threadIdx.x;

    const float s = ws[(size_t)b * NTAG + l]
                  + ws[(size_t)BATCH * NTAG + (size_t)b * NTAG + l];
    float m = s;
    #pragma unroll
    for (int d = 1; d < 64; d <<= 1) m = fmaxf(m, __shfl_xor(m, d, 64));
    float e = __builtin_amdgcn_exp2f((s - m) * L2E);
    #pragma unroll
    for (int d = 1; d < 64; d <<= 1) e += __shfl_xor(e, d, 64);
    const float den = fmaf(__builtin_amdgcn_logf(e), LN2, m);

    float num = 0.f;
    #pragma unroll
    for (int r = 0; r < 8; ++r) {
        const size_t tb = (size_t)(r * 64 + l) * BATCH + b;
        const int tv = target[tb];
        num += (float)mask[tb] * scores[tb * (size_t)TILE + tv];
    }
    #pragma unroll
    for (int d = 1; d < 64; d <<= 1) num += __shfl_xor(num, d, 64);

    if (l == 0) out[b] = (den - num) * (1.0f / BATCH);
}

extern "C" void kernel_launch(void* const* d_in, const int* in_sizes, int n_in,
                              void* d_out, int out_size, void* d_ws, size_t ws_size,
                              hipStream_t stream) {
    const float* scores = (const float*)d_in[0];
    const int*   target = (const int*)d_in[1];
    const int*   mask   = (const int*)d_in[2];
    float*       out    = (float*)d_out;
    float*       ws     = (float*)d_ws;
    (void)in_sizes; (void)n_in; (void)out_size; (void)ws_size;
    hipLaunchKernelGGL(crf_half_kernel, dim3(4 * BATCH), dim3(128), 0, stream,
                       scores, ws);
    hipLaunchKernelGGL(crf_combine_kernel, dim3(BATCH), dim3(64), 0, stream,
                       scores, target, mask, ws, out);
}